// Round 7
// baseline (3695.154 us; speedup 1.0000x reference)
//
#include <hip/hip_runtime.h>
#include <hip/hip_bf16.h>

#define NN 131072
#define EE 1048576
#define IN_F 74
#define HH 128
#define LL 3

using f32x4  = __attribute__((ext_vector_type(4))) float;
using f32x16 = __attribute__((ext_vector_type(16))) float;
using bf16x8 = __attribute__((ext_vector_type(8))) short;
typedef unsigned short ushort_t;
typedef unsigned int uint_t;

__device__ __forceinline__ short f2bf(float f) {
    __hip_bfloat16 b = __float2bfloat16(f);
    return __builtin_bit_cast(short, b);
}
__device__ __forceinline__ float bf2f(short s) {
    unsigned int u = ((unsigned int)(unsigned short)s) << 16;
    return __builtin_bit_cast(float, u);
}
__device__ __forceinline__ float bitf(uint_t u) { return __builtin_bit_cast(float, u); }
__device__ __forceinline__ float sigmoidf_(float x) { return 1.f / (1.f + __expf(-x)); }
__device__ __forceinline__ float tanhf_(float x)
{
    x = fminf(fmaxf(x, -15.f), 15.f);
    float e2 = __expf(2.f * x);
    return (e2 - 1.f) / (e2 + 1.f);
}

// ============ init: h = nf @ W_init -> bf16 hi/lo planes ============
__global__ __launch_bounds__(256) void k_init_gemm(
    const float* __restrict__ nf, const float* __restrict__ Wi,
    ushort_t* __restrict__ hhi, ushort_t* __restrict__ hlo)
{
    __shared__ float Wis[IN_F * HH];
    __shared__ float nfs[32 * IN_F];
    int b = blockIdx.x;
    int t = threadIdx.x;

    for (int i = t; i < IN_F * HH / 4; i += 256)
        reinterpret_cast<float4*>(Wis)[i] = reinterpret_cast<const float4*>(Wi)[i];
    {
        const float4* nf4 = reinterpret_cast<const float4*>(nf + (long)b * 32 * IN_F);
        for (int i = t; i < 32 * IN_F / 4; i += 256)
            reinterpret_cast<float4*>(nfs)[i] = nf4[i];
    }
    __syncthreads();

    int nl = t >> 3;
    int c0 = (t & 7) * 4;
    float acc[4][4];
#pragma unroll
    for (int hf = 0; hf < 4; ++hf)
#pragma unroll
        for (int j = 0; j < 4; ++j) acc[hf][j] = 0.f;

    const float* nrow = nfs + nl * IN_F;
#pragma unroll 2
    for (int k = 0; k < IN_F; ++k) {
        float a = nrow[k];
#pragma unroll
        for (int hf = 0; hf < 4; ++hf) {
            float4 wv = *reinterpret_cast<const float4*>(Wis + k * HH + hf * 32 + c0);
            acc[hf][0] += a * wv.x;
            acc[hf][1] += a * wv.y;
            acc[hf][2] += a * wv.z;
            acc[hf][3] += a * wv.w;
        }
    }

    int node = b * 32 + nl;
#pragma unroll
    for (int hf = 0; hf < 4; ++hf) {
        uint_t uh[2], ul[2];
#pragma unroll
        for (int p = 0; p < 2; ++p) {
            float v0 = acc[hf][p * 2], v1 = acc[hf][p * 2 + 1];
            short h0 = f2bf(v0), h1 = f2bf(v1);
            short l0 = f2bf(v0 - bf2f(h0)), l1 = f2bf(v1 - bf2f(h1));
            uh[p] = (uint_t)(ushort_t)h0 | ((uint_t)(ushort_t)h1 << 16);
            ul[p] = (uint_t)(ushort_t)l0 | ((uint_t)(ushort_t)l1 << 16);
        }
        long adr = (long)node * HH + hf * 32 + c0;
        *reinterpret_cast<uint2*>(hhi + adr) = make_uint2(uh[0], uh[1]);
        *reinterpret_cast<uint2*>(hlo + adr) = make_uint2(ul[0], ul[1]);
    }
}

// ============ CSR build ============
__global__ __launch_bounds__(256) void k_hist(const int* __restrict__ dsti, int* __restrict__ deg)
{
    int e = blockIdx.x * 256 + threadIdx.x;
    atomicAdd(&deg[dsti[e]], 1);
}

__global__ __launch_bounds__(256) void k_scan1(const int* __restrict__ deg, int* __restrict__ bsum)
{
    __shared__ int s[256];
    int b = blockIdx.x, t = threadIdx.x;
    int v = 0;
#pragma unroll
    for (int i = 0; i < 4; ++i) v += deg[b * 1024 + t * 4 + i];
    s[t] = v;
    __syncthreads();
    for (int st = 128; st > 0; st >>= 1) {
        if (t < st) s[t] += s[t + st];
        __syncthreads();
    }
    if (t == 0) bsum[b] = s[0];
}

__global__ void k_scan2(int* __restrict__ bsum, int nb)
{
    if (threadIdx.x == 0) {
        int run = 0;
        for (int i = 0; i < nb; ++i) { int v = bsum[i]; bsum[i] = run; run += v; }
    }
}

__global__ __launch_bounds__(256) void k_scan3(
    const int* __restrict__ deg, const int* __restrict__ bsum, int* __restrict__ row_start)
{
    __shared__ int s[256];
    int b = blockIdx.x, t = threadIdx.x;
    int base = b * 1024 + t * 4;
    int d0 = deg[base], d1 = deg[base + 1], d2 = deg[base + 2], d3 = deg[base + 3];
    int local = d0 + d1 + d2 + d3;
    s[t] = local;
    __syncthreads();
    for (int st = 1; st < 256; st <<= 1) {
        int v = (t >= st) ? s[t - st] : 0;
        __syncthreads();
        s[t] += v;
        __syncthreads();
    }
    int excl = s[t] - local + bsum[b];
    row_start[base] = excl;
    row_start[base + 1] = excl + d0;
    row_start[base + 2] = excl + d0 + d1;
    row_start[base + 3] = excl + d0 + d1 + d2;
    if (b == gridDim.x - 1 && t == 255) row_start[NN] = excl + local;
}

__global__ __launch_bounds__(256) void k_fill(
    const int* __restrict__ src, const int* __restrict__ dsti,
    const int* __restrict__ row_start, int* __restrict__ cursor, int* __restrict__ csr_src)
{
    int e = blockIdx.x * 256 + threadIdx.x;
    int d = dsti[e];
    int pos = atomicAdd(&cursor[d], 1);
    csr_src[row_start[d] + pos] = src[e];
}

// ============ weight split f32 -> (hi, lo) bf16 planes ============
__global__ __launch_bounds__(256) void k_split(
    const float* __restrict__ srcw, ushort_t* __restrict__ hi,
    ushort_t* __restrict__ lo, int n)
{
    int i = blockIdx.x * 256 + threadIdx.x;
    if (i >= n) return;
    float a = srcw[i];
    short h = f2bf(a);
    float rem = a - bf2f(h);
    hi[i] = (ushort_t)h;
    lo[i] = (ushort_t)f2bf(rem);
}

// ============ fused gather + x-GEMM ============
__global__ __launch_bounds__(256) void k_x(
    const ushort_t* __restrict__ hhi, const ushort_t* __restrict__ hlo,
    const int* __restrict__ row_start, const int* __restrict__ csr_src,
    const ushort_t* __restrict__ lWhi, const ushort_t* __restrict__ lWlo,
    const float* __restrict__ lb,
    ushort_t* __restrict__ xhi, ushort_t* __restrict__ xlo)
{
    __shared__ float aggs[32 * 128];
    char* abase = (char*)aggs;
    int n0 = blockIdx.x * 32;
    int t = threadIdx.x;
    int w = t >> 6, lane = t & 63;

    for (int i = 0; i < 8; ++i) {
        int nl = w * 8 + i;
        int node = n0 + nl;
        int e0 = row_start[node], e1 = row_start[node + 1];
        float a0 = 0.f, a1 = 0.f;
        int e = e0;
        for (; e + 3 < e1; e += 4) {
            int s0 = csr_src[e], s1 = csr_src[e + 1];
            int s2 = csr_src[e + 2], s3 = csr_src[e + 3];
            uint_t vh0 = *(const uint_t*)(hhi + (long)s0 * HH + lane * 2);
            uint_t vl0 = *(const uint_t*)(hlo + (long)s0 * HH + lane * 2);
            uint_t vh1 = *(const uint_t*)(hhi + (long)s1 * HH + lane * 2);
            uint_t vl1 = *(const uint_t*)(hlo + (long)s1 * HH + lane * 2);
            uint_t vh2 = *(const uint_t*)(hhi + (long)s2 * HH + lane * 2);
            uint_t vl2 = *(const uint_t*)(hlo + (long)s2 * HH + lane * 2);
            uint_t vh3 = *(const uint_t*)(hhi + (long)s3 * HH + lane * 2);
            uint_t vl3 = *(const uint_t*)(hlo + (long)s3 * HH + lane * 2);
            a0 += bitf(vh0 << 16) + bitf(vl0 << 16);
            a1 += bitf(vh0 & 0xffff0000u) + bitf(vl0 & 0xffff0000u);
            a0 += bitf(vh1 << 16) + bitf(vl1 << 16);
            a1 += bitf(vh1 & 0xffff0000u) + bitf(vl1 & 0xffff0000u);
            a0 += bitf(vh2 << 16) + bitf(vl2 << 16);
            a1 += bitf(vh2 & 0xffff0000u) + bitf(vl2 & 0xffff0000u);
            a0 += bitf(vh3 << 16) + bitf(vl3 << 16);
            a1 += bitf(vh3 & 0xffff0000u) + bitf(vl3 & 0xffff0000u);
        }
        for (; e < e1; ++e) {
            int s0 = csr_src[e];
            uint_t vh0 = *(const uint_t*)(hhi + (long)s0 * HH + lane * 2);
            uint_t vl0 = *(const uint_t*)(hlo + (long)s0 * HH + lane * 2);
            a0 += bitf(vh0 << 16) + bitf(vl0 << 16);
            a1 += bitf(vh0 & 0xffff0000u) + bitf(vl0 & 0xffff0000u);
        }
        int swz = (nl & 7) << 4;
        float2 st = make_float2(a0, a1);
        *reinterpret_cast<float2*>(abase + ((nl * 512 + lane * 8) ^ swz)) = st;
    }
    __syncthreads();

    int ng = w >> 1, jg = w & 1;
    int l16 = lane & 15, lq = lane >> 4;

    f32x4 acc[4];
#pragma unroll
    for (int js = 0; js < 4; ++js) acc[js] = (f32x4){0.f, 0.f, 0.f, 0.f};

#pragma unroll
    for (int kk = 0; kk < 4; ++kk) {
        int k0 = kk * 32;
        int nodeL = ng * 16 + l16;
        int kb = (k0 + lq * 8) * 4;
        int swz = (nodeL & 7) << 4;
        float4 f0 = *reinterpret_cast<const float4*>(abase + ((nodeL * 512 + kb) ^ swz));
        float4 f1 = *reinterpret_cast<const float4*>(abase + ((nodeL * 512 + kb + 16) ^ swz));
        float av[8] = {f0.x, f0.y, f0.z, f0.w, f1.x, f1.y, f1.z, f1.w};
        bf16x8 ahi, alo;
#pragma unroll
        for (int e = 0; e < 8; ++e) {
            short hh_ = f2bf(av[e]);
            ahi[e] = hh_;
            alo[e] = f2bf(av[e] - bf2f(hh_));
        }
#pragma unroll
        for (int js = 0; js < 4; ++js) {
            int jrow = jg * 64 + js * 16 + l16;
            bf16x8 Bh = *reinterpret_cast<const bf16x8*>(lWhi + (long)jrow * HH + k0 + lq * 8);
            bf16x8 Bl = *reinterpret_cast<const bf16x8*>(lWlo + (long)jrow * HH + k0 + lq * 8);
            acc[js] = __builtin_amdgcn_mfma_f32_16x16x32_bf16(ahi, Bh, acc[js], 0, 0, 0);
            acc[js] = __builtin_amdgcn_mfma_f32_16x16x32_bf16(ahi, Bl, acc[js], 0, 0, 0);
            acc[js] = __builtin_amdgcn_mfma_f32_16x16x32_bf16(alo, Bh, acc[js], 0, 0, 0);
        }
    }

#pragma unroll
    for (int js = 0; js < 4; ++js) {
        int j = jg * 64 + js * 16 + l16;
        float bj = lb[j];
#pragma unroll
        for (int r = 0; r < 4; ++r) {
            int node = n0 + ng * 16 + lq * 4 + r;
            float v = fmaxf(acc[js][r] + bj, 0.f);
            long adr = (long)node * HH + j;
            short hi_ = f2bf(v);
            xhi[adr] = (ushort_t)hi_;
            xlo[adr] = (ushort_t)f2bf(v - bf2f(hi_));
        }
    }
}

// ============ fused GRU v3: 4 lean passes, peak 2x f32x16 live, occupancy 4 ============
// Block: 64 nodes, 4 waves = (ng:2 x og:2). Wave: 32 nodes x 64 j per gate.
// Pass order: aNH -> aR (fold rn) -> aNI (fold n) -> aZ -> epilogue.
__global__ __launch_bounds__(256, 4) void k_gru(
    const ushort_t* __restrict__ xhi, const ushort_t* __restrict__ xlo,
    ushort_t* __restrict__ hhi, ushort_t* __restrict__ hlo,
    const ushort_t* __restrict__ Wihhi, const ushort_t* __restrict__ Wihlo,
    const ushort_t* __restrict__ Whhhi, const ushort_t* __restrict__ Whhlo,
    const float* __restrict__ bi, const float* __restrict__ bh)
{
    int t = threadIdx.x;
    int w = t >> 6, lane = t & 63;
    int ng = w >> 1, og = w & 1;
    int l31 = lane & 31, lh = lane >> 5;
    int n0 = blockIdx.x * 64;
    long arow = (long)(n0 + ng * 32 + l31) * HH;

    // ---- pass 1: aNH = h @ Whh_n ----
    f32x16 acc1[2];
#pragma unroll
    for (int js = 0; js < 2; ++js)
#pragma unroll
        for (int i = 0; i < 16; ++i) acc1[js][i] = 0.f;
#pragma unroll
    for (int kc = 0; kc < 8; ++kc) {
        int k = kc * 16 + lh * 8;
        bf16x8 ahi = *reinterpret_cast<const bf16x8*>(hhi + arow + k);
        bf16x8 alo = *reinterpret_cast<const bf16x8*>(hlo + arow + k);
#pragma unroll
        for (int js = 0; js < 2; ++js) {
            long rN = (long)(256 + og * 64 + js * 32 + l31) * HH + k;
            bf16x8 bNh = *reinterpret_cast<const bf16x8*>(Whhhi + rN);
            bf16x8 bNl = *reinterpret_cast<const bf16x8*>(Whhlo + rN);
            acc1[js] = __builtin_amdgcn_mfma_f32_32x32x16_bf16(ahi, bNh, acc1[js], 0, 0, 0);
            acc1[js] = __builtin_amdgcn_mfma_f32_32x32x16_bf16(ahi, bNl, acc1[js], 0, 0, 0);
            acc1[js] = __builtin_amdgcn_mfma_f32_32x32x16_bf16(alo, bNh, acc1[js], 0, 0, 0);
        }
    }

    // ---- pass 2: aR = [x|h] @ [Wih_r|Whh_r] (K=256) ----
    {
        f32x16 acc2[2];
#pragma unroll
        for (int js = 0; js < 2; ++js)
#pragma unroll
            for (int i = 0; i < 16; ++i) acc2[js][i] = 0.f;
#pragma unroll
        for (int half = 0; half < 2; ++half) {
            const ushort_t* Ah = half ? hhi : xhi;
            const ushort_t* Al = half ? hlo : xlo;
            const ushort_t* Bh = half ? Whhhi : Wihhi;
            const ushort_t* Bl = half ? Whhlo : Wihlo;
#pragma unroll
            for (int kc = 0; kc < 8; ++kc) {
                int k = kc * 16 + lh * 8;
                bf16x8 ahi = *reinterpret_cast<const bf16x8*>(Ah + arow + k);
                bf16x8 alo = *reinterpret_cast<const bf16x8*>(Al + arow + k);
#pragma unroll
                for (int js = 0; js < 2; ++js) {
                    long rR = (long)(og * 64 + js * 32 + l31) * HH + k;
                    bf16x8 bRh = *reinterpret_cast<const bf16x8*>(Bh + rR);
                    bf16x8 bRl = *reinterpret_cast<const bf16x8*>(Bl + rR);
                    acc2[js] = __builtin_amdgcn_mfma_f32_32x32x16_bf16(ahi, bRh, acc2[js], 0, 0, 0);
                    acc2[js] = __builtin_amdgcn_mfma_f32_32x32x16_bf16(ahi, bRl, acc2[js], 0, 0, 0);
                    acc2[js] = __builtin_amdgcn_mfma_f32_32x32x16_bf16(alo, bRh, acc2[js], 0, 0, 0);
                }
            }
        }
        // fold: acc1 := sigmoid(aR + biR + bhR) * (aNH + bhN)
#pragma unroll
        for (int js = 0; js < 2; ++js) {
            int jj = og * 64 + js * 32 + l31;
            float bR = bi[jj] + bh[jj];
            float bN_h = bh[256 + jj];
#pragma unroll
            for (int i = 0; i < 16; ++i)
                acc1[js][i] = sigmoidf_(acc2[js][i] + bR) * (acc1[js][i] + bN_h);
        }
    }

    // ---- pass 3: aNI = x @ Wih_n ; fold n = tanh(aNI + biN + rn) ----
    {
        f32x16 acc2[2];
#pragma unroll
        for (int js = 0; js < 2; ++js)
#pragma unroll
            for (int i = 0; i < 16; ++i) acc2[js][i] = 0.f;
#pragma unroll
        for (int kc = 0; kc < 8; ++kc) {
            int k = kc * 16 + lh * 8;
            bf16x8 ahi = *reinterpret_cast<const bf16x8*>(xhi + arow + k);
            bf16x8 alo = *reinterpret_cast<const bf16x8*>(xlo + arow + k);
#pragma unroll
            for (int js = 0; js < 2; ++js) {
                long rN = (long)(256 + og * 64 + js * 32 + l31) * HH + k;
                bf16x8 bNh = *reinterpret_cast<const bf16x8*>(Wihhi + rN);
                bf16x8 bNl = *reinterpret_cast<const bf16x8*>(Wihlo + rN);
                acc2[js] = __builtin_amdgcn_mfma_f32_32x32x16_bf16(ahi, bNh, acc2[js], 0, 0, 0);
                acc2[js] = __builtin_amdgcn_mfma_f32_32x32x16_bf16(ahi, bNl, acc2[js], 0, 0, 0);
                acc2[js] = __builtin_amdgcn_mfma_f32_32x32x16_bf16(alo, bNh, acc2[js], 0, 0, 0);
            }
        }
#pragma unroll
        for (int js = 0; js < 2; ++js) {
            int jj = og * 64 + js * 32 + l31;
            float bN_i = bi[256 + jj];
#pragma unroll
            for (int i = 0; i < 16; ++i)
                acc1[js][i] = tanhf_(acc2[js][i] + bN_i + acc1[js][i]);
        }
    }

    // ---- pass 4: aZ = [x|h] @ [Wih_z|Whh_z] (K=256) ----
    f32x16 accZ[2];
#pragma unroll
    for (int js = 0; js < 2; ++js)
#pragma unroll
        for (int i = 0; i < 16; ++i) accZ[js][i] = 0.f;
#pragma unroll
    for (int half = 0; half < 2; ++half) {
        const ushort_t* Ah = half ? hhi : xhi;
        const ushort_t* Al = half ? hlo : xlo;
        const ushort_t* Bh = half ? Whhhi : Wihhi;
        const ushort_t* Bl = half ? Whhlo : Wihlo;
#pragma unroll
        for (int kc = 0; kc < 8; ++kc) {
            int k = kc * 16 + lh * 8;
            bf16x8 ahi = *reinterpret_cast<const bf16x8*>(Ah + arow + k);
            bf16x8 alo = *reinterpret_cast<const bf16x8*>(Al + arow + k);
#pragma unroll
            for (int js = 0; js < 2; ++js) {
                long rZ = (long)(128 + og * 64 + js * 32 + l31) * HH + k;
                bf16x8 bZh = *reinterpret_cast<const bf16x8*>(Bh + rZ);
                bf16x8 bZl = *reinterpret_cast<const bf16x8*>(Bl + rZ);
                accZ[js] = __builtin_amdgcn_mfma_f32_32x32x16_bf16(ahi, bZh, accZ[js], 0, 0, 0);
                accZ[js] = __builtin_amdgcn_mfma_f32_32x32x16_bf16(ahi, bZl, accZ[js], 0, 0, 0);
                accZ[js] = __builtin_amdgcn_mfma_f32_32x32x16_bf16(alo, bZh, accZ[js], 0, 0, 0);
            }
        }
    }

    // all h-plane reads done; safe for in-place h update after barrier
    __syncthreads();

    // ---- epilogue: z = sigmoid(aZ + bZ); h' = (1-z)*n + z*h_old ----
#pragma unroll
    for (int js = 0; js < 2; ++js) {
        int jj = og * 64 + js * 32 + l31;
        float bZ = bi[128 + jj] + bh[128 + jj];
#pragma unroll
        for (int reg = 0; reg < 16; ++reg) {
            int ndl = ng * 32 + (reg & 3) + 8 * (reg >> 2) + 4 * lh;
            long adr = (long)(n0 + ndl) * HH + jj;
            float hold = bf2f((short)hhi[adr]) + bf2f((short)hlo[adr]);
            float zv = sigmoidf_(accZ[js][reg] + bZ);
            float hp = (1.f - zv) * acc1[js][reg] + zv * hold;
            short hi_ = f2bf(hp);
            hhi[adr] = (ushort_t)hi_;
            hlo[adr] = (ushort_t)f2bf(hp - bf2f(hi_));
        }
    }
}

// ============ final: d_out = hhi + hlo (f32) ============
__global__ __launch_bounds__(256) void k_copy(
    const uint_t* __restrict__ hhi, const uint_t* __restrict__ hlo,
    float2* __restrict__ out)
{
    long i = (long)blockIdx.x * 256 + threadIdx.x;
    uint_t vh = hhi[i], vl = hlo[i];
    float2 o;
    o.x = bitf(vh << 16) + bitf(vl << 16);
    o.y = bitf(vh & 0xffff0000u) + bitf(vl & 0xffff0000u);
    out[i] = o;
}

extern "C" void kernel_launch(void* const* d_in, const int* in_sizes, int n_in,
                              void* d_out, int out_size, void* d_ws, size_t ws_size,
                              hipStream_t stream)
{
    const float* nf     = (const float*)d_in[0];
    const int*   src    = (const int*)d_in[1];
    const int*   dsti   = (const int*)d_in[2];
    const float* W_init = (const float*)d_in[3];
    const float* lin_W  = (const float*)d_in[4];
    const float* lin_b  = (const float*)d_in[5];
    const float* Wih    = (const float*)d_in[6];
    const float* Whh    = (const float*)d_in[7];
    const float* bih    = (const float*)d_in[8];
    const float* bhh    = (const float*)d_in[9];

    char* ws = (char*)d_ws;
    ushort_t* hhi = (ushort_t*)ws;
    ushort_t* hlo = (ushort_t*)(ws + (32ull << 20));
    ushort_t* xhi = (ushort_t*)(ws + (64ull << 20));
    ushort_t* xlo = (ushort_t*)(ws + (96ull << 20));
    int* deg    = (int*)(ws + (64ull << 20));
    int* cursor = (int*)(ws + (64ull << 20) + (1 << 20));
    int* bsum   = (int*)(ws + (64ull << 20) + (2 << 20));

    char* ob = (char*)d_out;
    int* row_start = (int*)ob;
    int* csr_src   = (int*)(ob + (1ull << 20));
    ushort_t* lWhi  = (ushort_t*)(ob + (6ull << 20));
    ushort_t* lWlo  = lWhi  + 3 * 128 * 128;
    ushort_t* Wihhi = lWlo  + 3 * 128 * 128;
    ushort_t* Wihlo = Wihhi + 3 * 384 * 128;
    ushort_t* Whhhi = Wihlo + 3 * 384 * 128;
    ushort_t* Whhlo = Whhhi + 3 * 384 * 128;

    k_init_gemm<<<NN / 32, 256, 0, stream>>>(nf, W_init, hhi, hlo);

    hipMemsetAsync(deg, 0, (size_t)NN * 4, stream);
    hipMemsetAsync(cursor, 0, (size_t)NN * 4, stream);
    k_hist<<<EE / 256, 256, 0, stream>>>(dsti, deg);
    k_scan1<<<NN / 1024, 256, 0, stream>>>(deg, bsum);
    k_scan2<<<1, 64, 0, stream>>>(bsum, NN / 1024);
    k_scan3<<<NN / 1024, 256, 0, stream>>>(deg, bsum, row_start);
    k_fill<<<EE / 256, 256, 0, stream>>>(src, dsti, row_start, cursor, csr_src);

    k_split<<<(3 * 128 * 128 + 255) / 256, 256, 0, stream>>>(lin_W, lWhi, lWlo, 3 * 128 * 128);
    k_split<<<(3 * 384 * 128 + 255) / 256, 256, 0, stream>>>(Wih, Wihhi, Wihlo, 3 * 384 * 128);
    k_split<<<(3 * 384 * 128 + 255) / 256, 256, 0, stream>>>(Whh, Whhhi, Whhlo, 3 * 384 * 128);

    for (int l = 0; l < LL; ++l) {
        k_x<<<NN / 32, 256, 0, stream>>>(
            hhi, hlo, row_start, csr_src,
            lWhi + (long)l * 128 * 128, lWlo + (long)l * 128 * 128,
            lin_b + (long)l * 128, xhi, xlo);
        k_gru<<<NN / 64, 256, 0, stream>>>(
            xhi, xlo, hhi, hlo,
            Wihhi + (long)l * 384 * 128, Wihlo + (long)l * 384 * 128,
            Whhhi + (long)l * 384 * 128, Whhlo + (long)l * 384 * 128,
            bih + (long)l * 384, bhh + (long)l * 384);
    }

    k_copy<<<NN * HH / 2 / 256, 256, 0, stream>>>((const uint_t*)hhi, (const uint_t*)hlo, (float2*)d_out);
}

// Round 8
// 1388.413 us; speedup vs baseline: 2.6614x; 2.6614x over previous
//
#include <hip/hip_runtime.h>
#include <hip/hip_bf16.h>

#define NN 131072
#define EE 1048576
#define IN_F 74
#define HH 128
#define LL 3

using f32x4  = __attribute__((ext_vector_type(4))) float;
using f32x16 = __attribute__((ext_vector_type(16))) float;
using bf16x8 = __attribute__((ext_vector_type(8))) short;
typedef unsigned short ushort_t;
typedef unsigned int uint_t;

__device__ __forceinline__ short f2bf(float f) {
    __hip_bfloat16 b = __float2bfloat16(f);
    return __builtin_bit_cast(short, b);
}
__device__ __forceinline__ float bf2f(short s) {
    unsigned int u = ((unsigned int)(unsigned short)s) << 16;
    return __builtin_bit_cast(float, u);
}
__device__ __forceinline__ float bitf(uint_t u) { return __builtin_bit_cast(float, u); }
__device__ __forceinline__ float sigmoidf_(float x) { return 1.f / (1.f + __expf(-x)); }
__device__ __forceinline__ float tanhf_(float x)
{
    x = fminf(fmaxf(x, -15.f), 15.f);
    float e2 = __expf(2.f * x);
    return (e2 - 1.f) / (e2 + 1.f);
}

// ============ init: h = nf @ W_init -> bf16 hi/lo planes ============
__global__ __launch_bounds__(256) void k_init_gemm(
    const float* __restrict__ nf, const float* __restrict__ Wi,
    ushort_t* __restrict__ hhi, ushort_t* __restrict__ hlo)
{
    __shared__ float Wis[IN_F * HH];
    __shared__ float nfs[32 * IN_F];
    int b = blockIdx.x;
    int t = threadIdx.x;

    for (int i = t; i < IN_F * HH / 4; i += 256)
        reinterpret_cast<float4*>(Wis)[i] = reinterpret_cast<const float4*>(Wi)[i];
    {
        const float4* nf4 = reinterpret_cast<const float4*>(nf + (long)b * 32 * IN_F);
        for (int i = t; i < 32 * IN_F / 4; i += 256)
            reinterpret_cast<float4*>(nfs)[i] = nf4[i];
    }
    __syncthreads();

    int nl = t >> 3;
    int c0 = (t & 7) * 4;
    float acc[4][4];
#pragma unroll
    for (int hf = 0; hf < 4; ++hf)
#pragma unroll
        for (int j = 0; j < 4; ++j) acc[hf][j] = 0.f;

    const float* nrow = nfs + nl * IN_F;
#pragma unroll 2
    for (int k = 0; k < IN_F; ++k) {
        float a = nrow[k];
#pragma unroll
        for (int hf = 0; hf < 4; ++hf) {
            float4 wv = *reinterpret_cast<const float4*>(Wis + k * HH + hf * 32 + c0);
            acc[hf][0] += a * wv.x;
            acc[hf][1] += a * wv.y;
            acc[hf][2] += a * wv.z;
            acc[hf][3] += a * wv.w;
        }
    }

    int node = b * 32 + nl;
#pragma unroll
    for (int hf = 0; hf < 4; ++hf) {
        uint_t uh[2], ul[2];
#pragma unroll
        for (int p = 0; p < 2; ++p) {
            float v0 = acc[hf][p * 2], v1 = acc[hf][p * 2 + 1];
            short h0 = f2bf(v0), h1 = f2bf(v1);
            short l0 = f2bf(v0 - bf2f(h0)), l1 = f2bf(v1 - bf2f(h1));
            uh[p] = (uint_t)(ushort_t)h0 | ((uint_t)(ushort_t)h1 << 16);
            ul[p] = (uint_t)(ushort_t)l0 | ((uint_t)(ushort_t)l1 << 16);
        }
        long adr = (long)node * HH + hf * 32 + c0;
        *reinterpret_cast<uint2*>(hhi + adr) = make_uint2(uh[0], uh[1]);
        *reinterpret_cast<uint2*>(hlo + adr) = make_uint2(ul[0], ul[1]);
    }
}

// ============ CSR build ============
__global__ __launch_bounds__(256) void k_hist(const int* __restrict__ dsti, int* __restrict__ deg)
{
    int e = blockIdx.x * 256 + threadIdx.x;
    atomicAdd(&deg[dsti[e]], 1);
}

__global__ __launch_bounds__(256) void k_scan1(const int* __restrict__ deg, int* __restrict__ bsum)
{
    __shared__ int s[256];
    int b = blockIdx.x, t = threadIdx.x;
    int v = 0;
#pragma unroll
    for (int i = 0; i < 4; ++i) v += deg[b * 1024 + t * 4 + i];
    s[t] = v;
    __syncthreads();
    for (int st = 128; st > 0; st >>= 1) {
        if (t < st) s[t] += s[t + st];
        __syncthreads();
    }
    if (t == 0) bsum[b] = s[0];
}

__global__ void k_scan2(int* __restrict__ bsum, int nb)
{
    if (threadIdx.x == 0) {
        int run = 0;
        for (int i = 0; i < nb; ++i) { int v = bsum[i]; bsum[i] = run; run += v; }
    }
}

__global__ __launch_bounds__(256) void k_scan3(
    const int* __restrict__ deg, const int* __restrict__ bsum, int* __restrict__ row_start)
{
    __shared__ int s[256];
    int b = blockIdx.x, t = threadIdx.x;
    int base = b * 1024 + t * 4;
    int d0 = deg[base], d1 = deg[base + 1], d2 = deg[base + 2], d3 = deg[base + 3];
    int local = d0 + d1 + d2 + d3;
    s[t] = local;
    __syncthreads();
    for (int st = 1; st < 256; st <<= 1) {
        int v = (t >= st) ? s[t - st] : 0;
        __syncthreads();
        s[t] += v;
        __syncthreads();
    }
    int excl = s[t] - local + bsum[b];
    row_start[base] = excl;
    row_start[base + 1] = excl + d0;
    row_start[base + 2] = excl + d0 + d1;
    row_start[base + 3] = excl + d0 + d1 + d2;
    if (b == gridDim.x - 1 && t == 255) row_start[NN] = excl + local;
}

__global__ __launch_bounds__(256) void k_fill(
    const int* __restrict__ src, const int* __restrict__ dsti,
    const int* __restrict__ row_start, int* __restrict__ cursor, int* __restrict__ csr_src)
{
    int e = blockIdx.x * 256 + threadIdx.x;
    int d = dsti[e];
    int pos = atomicAdd(&cursor[d], 1);
    csr_src[row_start[d] + pos] = src[e];
}

// ============ weight split f32 -> (hi, lo) bf16 planes ============
__global__ __launch_bounds__(256) void k_split(
    const float* __restrict__ srcw, ushort_t* __restrict__ hi,
    ushort_t* __restrict__ lo, int n)
{
    int i = blockIdx.x * 256 + threadIdx.x;
    if (i >= n) return;
    float a = srcw[i];
    short h = f2bf(a);
    float rem = a - bf2f(h);
    hi[i] = (ushort_t)h;
    lo[i] = (ushort_t)f2bf(rem);
}

// ============ fused gather + x-GEMM ============
__global__ __launch_bounds__(256) void k_x(
    const ushort_t* __restrict__ hhi, const ushort_t* __restrict__ hlo,
    const int* __restrict__ row_start, const int* __restrict__ csr_src,
    const ushort_t* __restrict__ lWhi, const ushort_t* __restrict__ lWlo,
    const float* __restrict__ lb,
    ushort_t* __restrict__ xhi, ushort_t* __restrict__ xlo)
{
    __shared__ float aggs[32 * 128];
    char* abase = (char*)aggs;
    int n0 = blockIdx.x * 32;
    int t = threadIdx.x;
    int w = t >> 6, lane = t & 63;

    for (int i = 0; i < 8; ++i) {
        int nl = w * 8 + i;
        int node = n0 + nl;
        int e0 = row_start[node], e1 = row_start[node + 1];
        float a0 = 0.f, a1 = 0.f;
        int e = e0;
        for (; e + 3 < e1; e += 4) {
            int s0 = csr_src[e], s1 = csr_src[e + 1];
            int s2 = csr_src[e + 2], s3 = csr_src[e + 3];
            uint_t vh0 = *(const uint_t*)(hhi + (long)s0 * HH + lane * 2);
            uint_t vl0 = *(const uint_t*)(hlo + (long)s0 * HH + lane * 2);
            uint_t vh1 = *(const uint_t*)(hhi + (long)s1 * HH + lane * 2);
            uint_t vl1 = *(const uint_t*)(hlo + (long)s1 * HH + lane * 2);
            uint_t vh2 = *(const uint_t*)(hhi + (long)s2 * HH + lane * 2);
            uint_t vl2 = *(const uint_t*)(hlo + (long)s2 * HH + lane * 2);
            uint_t vh3 = *(const uint_t*)(hhi + (long)s3 * HH + lane * 2);
            uint_t vl3 = *(const uint_t*)(hlo + (long)s3 * HH + lane * 2);
            a0 += bitf(vh0 << 16) + bitf(vl0 << 16);
            a1 += bitf(vh0 & 0xffff0000u) + bitf(vl0 & 0xffff0000u);
            a0 += bitf(vh1 << 16) + bitf(vl1 << 16);
            a1 += bitf(vh1 & 0xffff0000u) + bitf(vl1 & 0xffff0000u);
            a0 += bitf(vh2 << 16) + bitf(vl2 << 16);
            a1 += bitf(vh2 & 0xffff0000u) + bitf(vl2 & 0xffff0000u);
            a0 += bitf(vh3 << 16) + bitf(vl3 << 16);
            a1 += bitf(vh3 & 0xffff0000u) + bitf(vl3 & 0xffff0000u);
        }
        for (; e < e1; ++e) {
            int s0 = csr_src[e];
            uint_t vh0 = *(const uint_t*)(hhi + (long)s0 * HH + lane * 2);
            uint_t vl0 = *(const uint_t*)(hlo + (long)s0 * HH + lane * 2);
            a0 += bitf(vh0 << 16) + bitf(vl0 << 16);
            a1 += bitf(vh0 & 0xffff0000u) + bitf(vl0 & 0xffff0000u);
        }
        int swz = (nl & 7) << 4;
        float2 st = make_float2(a0, a1);
        *reinterpret_cast<float2*>(abase + ((nl * 512 + lane * 8) ^ swz)) = st;
    }
    __syncthreads();

    int ng = w >> 1, jg = w & 1;
    int l16 = lane & 15, lq = lane >> 4;

    f32x4 acc[4];
#pragma unroll
    for (int js = 0; js < 4; ++js) acc[js] = (f32x4){0.f, 0.f, 0.f, 0.f};

#pragma unroll
    for (int kk = 0; kk < 4; ++kk) {
        int k0 = kk * 32;
        int nodeL = ng * 16 + l16;
        int kb = (k0 + lq * 8) * 4;
        int swz = (nodeL & 7) << 4;
        float4 f0 = *reinterpret_cast<const float4*>(abase + ((nodeL * 512 + kb) ^ swz));
        float4 f1 = *reinterpret_cast<const float4*>(abase + ((nodeL * 512 + kb + 16) ^ swz));
        float av[8] = {f0.x, f0.y, f0.z, f0.w, f1.x, f1.y, f1.z, f1.w};
        bf16x8 ahi, alo;
#pragma unroll
        for (int e = 0; e < 8; ++e) {
            short hh_ = f2bf(av[e]);
            ahi[e] = hh_;
            alo[e] = f2bf(av[e] - bf2f(hh_));
        }
#pragma unroll
        for (int js = 0; js < 4; ++js) {
            int jrow = jg * 64 + js * 16 + l16;
            bf16x8 Bh = *reinterpret_cast<const bf16x8*>(lWhi + (long)jrow * HH + k0 + lq * 8);
            bf16x8 Bl = *reinterpret_cast<const bf16x8*>(lWlo + (long)jrow * HH + k0 + lq * 8);
            acc[js] = __builtin_amdgcn_mfma_f32_16x16x32_bf16(ahi, Bh, acc[js], 0, 0, 0);
            acc[js] = __builtin_amdgcn_mfma_f32_16x16x32_bf16(ahi, Bl, acc[js], 0, 0, 0);
            acc[js] = __builtin_amdgcn_mfma_f32_16x16x32_bf16(alo, Bh, acc[js], 0, 0, 0);
        }
    }

#pragma unroll
    for (int js = 0; js < 4; ++js) {
        int j = jg * 64 + js * 16 + l16;
        float bj = lb[j];
#pragma unroll
        for (int r = 0; r < 4; ++r) {
            int node = n0 + ng * 16 + lq * 4 + r;
            float v = fmaxf(acc[js][r] + bj, 0.f);
            long adr = (long)node * HH + j;
            short hi_ = f2bf(v);
            xhi[adr] = (ushort_t)hi_;
            xlo[adr] = (ushort_t)f2bf(v - bf2f(hi_));
        }
    }
}

// ============ fused GRU v4: 8 waves x (32 nodes x 32 j), 4 lean passes ============
// Block: 64 nodes, 512 threads. wave w: ng = w>>2 (node group), og = w&3 (j group).
// Peak live accumulators: 2x f32x16 = 32 VGPRs. NO launch_bounds (r7 spill lesson).
__global__ void k_gru(
    const ushort_t* __restrict__ xhi, const ushort_t* __restrict__ xlo,
    ushort_t* __restrict__ hhi, ushort_t* __restrict__ hlo,
    const ushort_t* __restrict__ Wihhi, const ushort_t* __restrict__ Wihlo,
    const ushort_t* __restrict__ Whhhi, const ushort_t* __restrict__ Whhlo,
    const float* __restrict__ bi, const float* __restrict__ bh)
{
    int t = threadIdx.x;
    int w = t >> 6, lane = t & 63;
    int ng = w >> 2, og = w & 3;
    int l31 = lane & 31, lh = lane >> 5;
    int n0 = blockIdx.x * 64;
    long arow = (long)(n0 + ng * 32 + l31) * HH;
    int jj = og * 32 + l31;   // this wave's j column (B row index)

    // ---- pass 1: acc1 = h @ Whh_n ----
    f32x16 acc1;
#pragma unroll
    for (int i = 0; i < 16; ++i) acc1[i] = 0.f;
    {
        long rN = (long)(256 + jj) * HH;
#pragma unroll
        for (int kc = 0; kc < 8; ++kc) {
            int k = kc * 16 + lh * 8;
            bf16x8 ahi = *reinterpret_cast<const bf16x8*>(hhi + arow + k);
            bf16x8 alo = *reinterpret_cast<const bf16x8*>(hlo + arow + k);
            bf16x8 bNh = *reinterpret_cast<const bf16x8*>(Whhhi + rN + k);
            bf16x8 bNl = *reinterpret_cast<const bf16x8*>(Whhlo + rN + k);
            acc1 = __builtin_amdgcn_mfma_f32_32x32x16_bf16(ahi, bNh, acc1, 0, 0, 0);
            acc1 = __builtin_amdgcn_mfma_f32_32x32x16_bf16(ahi, bNl, acc1, 0, 0, 0);
            acc1 = __builtin_amdgcn_mfma_f32_32x32x16_bf16(alo, bNh, acc1, 0, 0, 0);
        }
    }

    // ---- pass 2: acc2 = [x|h] @ [Wih_r|Whh_r]; fold rn ----
    {
        f32x16 acc2;
#pragma unroll
        for (int i = 0; i < 16; ++i) acc2[i] = 0.f;
        long rR = (long)jj * HH;
#pragma unroll
        for (int half = 0; half < 2; ++half) {
            const ushort_t* Ah = half ? hhi : xhi;
            const ushort_t* Al = half ? hlo : xlo;
            const ushort_t* Bh = half ? Whhhi : Wihhi;
            const ushort_t* Bl = half ? Whhlo : Wihlo;
#pragma unroll
            for (int kc = 0; kc < 8; ++kc) {
                int k = kc * 16 + lh * 8;
                bf16x8 ahi = *reinterpret_cast<const bf16x8*>(Ah + arow + k);
                bf16x8 alo = *reinterpret_cast<const bf16x8*>(Al + arow + k);
                bf16x8 bRh = *reinterpret_cast<const bf16x8*>(Bh + rR + k);
                bf16x8 bRl = *reinterpret_cast<const bf16x8*>(Bl + rR + k);
                acc2 = __builtin_amdgcn_mfma_f32_32x32x16_bf16(ahi, bRh, acc2, 0, 0, 0);
                acc2 = __builtin_amdgcn_mfma_f32_32x32x16_bf16(ahi, bRl, acc2, 0, 0, 0);
                acc2 = __builtin_amdgcn_mfma_f32_32x32x16_bf16(alo, bRh, acc2, 0, 0, 0);
            }
        }
        float bR = bi[jj] + bh[jj];
        float bN_h = bh[256 + jj];
#pragma unroll
        for (int i = 0; i < 16; ++i)
            acc1[i] = sigmoidf_(acc2[i] + bR) * (acc1[i] + bN_h);
    }

    // ---- pass 3: acc2 = x @ Wih_n; fold n = tanh ----
    {
        f32x16 acc2;
#pragma unroll
        for (int i = 0; i < 16; ++i) acc2[i] = 0.f;
        long rN = (long)(256 + jj) * HH;
#pragma unroll
        for (int kc = 0; kc < 8; ++kc) {
            int k = kc * 16 + lh * 8;
            bf16x8 ahi = *reinterpret_cast<const bf16x8*>(xhi + arow + k);
            bf16x8 alo = *reinterpret_cast<const bf16x8*>(xlo + arow + k);
            bf16x8 bNh = *reinterpret_cast<const bf16x8*>(Wihhi + rN + k);
            bf16x8 bNl = *reinterpret_cast<const bf16x8*>(Wihlo + rN + k);
            acc2 = __builtin_amdgcn_mfma_f32_32x32x16_bf16(ahi, bNh, acc2, 0, 0, 0);
            acc2 = __builtin_amdgcn_mfma_f32_32x32x16_bf16(ahi, bNl, acc2, 0, 0, 0);
            acc2 = __builtin_amdgcn_mfma_f32_32x32x16_bf16(alo, bNh, acc2, 0, 0, 0);
        }
        float bN_i = bi[256 + jj];
#pragma unroll
        for (int i = 0; i < 16; ++i)
            acc1[i] = tanhf_(acc2[i] + bN_i + acc1[i]);
    }

    // ---- pass 4: accZ = [x|h] @ [Wih_z|Whh_z] ----
    f32x16 accZ;
#pragma unroll
    for (int i = 0; i < 16; ++i) accZ[i] = 0.f;
    {
        long rZ = (long)(128 + jj) * HH;
#pragma unroll
        for (int half = 0; half < 2; ++half) {
            const ushort_t* Ah = half ? hhi : xhi;
            const ushort_t* Al = half ? hlo : xlo;
            const ushort_t* Bh = half ? Whhhi : Wihhi;
            const ushort_t* Bl = half ? Whhlo : Wihlo;
#pragma unroll
            for (int kc = 0; kc < 8; ++kc) {
                int k = kc * 16 + lh * 8;
                bf16x8 ahi = *reinterpret_cast<const bf16x8*>(Ah + arow + k);
                bf16x8 alo = *reinterpret_cast<const bf16x8*>(Al + arow + k);
                bf16x8 bZh = *reinterpret_cast<const bf16x8*>(Bh + rZ + k);
                bf16x8 bZl = *reinterpret_cast<const bf16x8*>(Bl + rZ + k);
                accZ = __builtin_amdgcn_mfma_f32_32x32x16_bf16(ahi, bZh, accZ, 0, 0, 0);
                accZ = __builtin_amdgcn_mfma_f32_32x32x16_bf16(ahi, bZl, accZ, 0, 0, 0);
                accZ = __builtin_amdgcn_mfma_f32_32x32x16_bf16(alo, bZh, accZ, 0, 0, 0);
            }
        }
    }

    // all h-plane reads done; safe for in-place h update after barrier
    __syncthreads();

    // ---- epilogue: z = sigmoid(accZ + bZ); h' = (1-z)*n + z*h_old ----
    {
        float bZ = bi[128 + jj] + bh[128 + jj];
#pragma unroll
        for (int reg = 0; reg < 16; ++reg) {
            int ndl = ng * 32 + (reg & 3) + 8 * (reg >> 2) + 4 * lh;
            long adr = (long)(n0 + ndl) * HH + jj;
            float hold = bf2f((short)hhi[adr]) + bf2f((short)hlo[adr]);
            float zv = sigmoidf_(accZ[reg] + bZ);
            float hp = (1.f - zv) * acc1[reg] + zv * hold;
            short hi_ = f2bf(hp);
            hhi[adr] = (ushort_t)hi_;
            hlo[adr] = (ushort_t)f2bf(hp - bf2f(hi_));
        }
    }
}

// ============ final: d_out = hhi + hlo (f32) ============
__global__ __launch_bounds__(256) void k_copy(
    const uint_t* __restrict__ hhi, const uint_t* __restrict__ hlo,
    float2* __restrict__ out)
{
    long i = (long)blockIdx.x * 256 + threadIdx.x;
    uint_t vh = hhi[i], vl = hlo[i];
    float2 o;
    o.x = bitf(vh << 16) + bitf(vl << 16);
    o.y = bitf(vh & 0xffff0000u) + bitf(vl & 0xffff0000u);
    out[i] = o;
}

extern "C" void kernel_launch(void* const* d_in, const int* in_sizes, int n_in,
                              void* d_out, int out_size, void* d_ws, size_t ws_size,
                              hipStream_t stream)
{
    const float* nf     = (const float*)d_in[0];
    const int*   src    = (const int*)d_in[1];
    const int*   dsti   = (const int*)d_in[2];
    const float* W_init = (const float*)d_in[3];
    const float* lin_W  = (const float*)d_in[4];
    const float* lin_b  = (const float*)d_in[5];
    const float* Wih    = (const float*)d_in[6];
    const float* Whh    = (const float*)d_in[7];
    const float* bih    = (const float*)d_in[8];
    const float* bhh    = (const float*)d_in[9];

    char* ws = (char*)d_ws;
    ushort_t* hhi = (ushort_t*)ws;
    ushort_t* hlo = (ushort_t*)(ws + (32ull << 20));
    ushort_t* xhi = (ushort_t*)(ws + (64ull << 20));
    ushort_t* xlo = (ushort_t*)(ws + (96ull << 20));
    int* deg    = (int*)(ws + (64ull << 20));
    int* cursor = (int*)(ws + (64ull << 20) + (1 << 20));
    int* bsum   = (int*)(ws + (64ull << 20) + (2 << 20));

    char* ob = (char*)d_out;
    int* row_start = (int*)ob;
    int* csr_src   = (int*)(ob + (1ull << 20));
    ushort_t* lWhi  = (ushort_t*)(ob + (6ull << 20));
    ushort_t* lWlo  = lWhi  + 3 * 128 * 128;
    ushort_t* Wihhi = lWlo  + 3 * 128 * 128;
    ushort_t* Wihlo = Wihhi + 3 * 384 * 128;
    ushort_t* Whhhi = Wihlo + 3 * 384 * 128;
    ushort_t* Whhlo = Whhhi + 3 * 384 * 128;

    k_init_gemm<<<NN / 32, 256, 0, stream>>>(nf, W_init, hhi, hlo);

    hipMemsetAsync(deg, 0, (size_t)NN * 4, stream);
    hipMemsetAsync(cursor, 0, (size_t)NN * 4, stream);
    k_hist<<<EE / 256, 256, 0, stream>>>(dsti, deg);
    k_scan1<<<NN / 1024, 256, 0, stream>>>(deg, bsum);
    k_scan2<<<1, 64, 0, stream>>>(bsum, NN / 1024);
    k_scan3<<<NN / 1024, 256, 0, stream>>>(deg, bsum, row_start);
    k_fill<<<EE / 256, 256, 0, stream>>>(src, dsti, row_start, cursor, csr_src);

    k_split<<<(3 * 128 * 128 + 255) / 256, 256, 0, stream>>>(lin_W, lWhi, lWlo, 3 * 128 * 128);
    k_split<<<(3 * 384 * 128 + 255) / 256, 256, 0, stream>>>(Wih, Wihhi, Wihlo, 3 * 384 * 128);
    k_split<<<(3 * 384 * 128 + 255) / 256, 256, 0, stream>>>(Whh, Whhhi, Whhlo, 3 * 384 * 128);

    for (int l = 0; l < LL; ++l) {
        k_x<<<NN / 32, 256, 0, stream>>>(
            hhi, hlo, row_start, csr_src,
            lWhi + (long)l * 128 * 128, lWlo + (long)l * 128 * 128,
            lin_b + (long)l * 128, xhi, xlo);
        k_gru<<<NN / 64, 512, 0, stream>>>(
            xhi, xlo, hhi, hlo,
            Wihhi + (long)l * 384 * 128, Wihlo + (long)l * 384 * 128,
            Whhhi + (long)l * 384 * 128, Whhlo + (long)l * 384 * 128,
            bih + (long)l * 384, bhh + (long)l * 384);
    }

    k_copy<<<NN * HH / 2 / 256, 256, 0, stream>>>((const uint_t*)hhi, (const uint_t*)hlo, (float2*)d_out);
}

// Round 9
// 981.320 us; speedup vs baseline: 3.7655x; 1.4148x over previous
//
#include <hip/hip_runtime.h>
#include <hip/hip_bf16.h>

#define NN 131072
#define EE 1048576
#define IN_F 74
#define HH 128
#define LL 3

using f32x4  = __attribute__((ext_vector_type(4))) float;
using f32x16 = __attribute__((ext_vector_type(16))) float;
using bf16x8 = __attribute__((ext_vector_type(8))) short;
typedef unsigned short ushort_t;
typedef unsigned int uint_t;

__device__ __forceinline__ short f2bf(float f) {
    __hip_bfloat16 b = __float2bfloat16(f);
    return __builtin_bit_cast(short, b);
}
__device__ __forceinline__ float bf2f(short s) {
    unsigned int u = ((unsigned int)(unsigned short)s) << 16;
    return __builtin_bit_cast(float, u);
}
__device__ __forceinline__ float bitf(uint_t u) { return __builtin_bit_cast(float, u); }
__device__ __forceinline__ float sigmoidf_(float x) { return 1.f / (1.f + __expf(-x)); }
__device__ __forceinline__ float tanhf_(float x)
{
    x = fminf(fmaxf(x, -15.f), 15.f);
    float e2 = __expf(2.f * x);
    return (e2 - 1.f) / (e2 + 1.f);
}

// ============ init: h = nf @ W_init -> bf16 hi/lo planes ============
__global__ __launch_bounds__(256) void k_init_gemm(
    const float* __restrict__ nf, const float* __restrict__ Wi,
    ushort_t* __restrict__ hhi, ushort_t* __restrict__ hlo)
{
    __shared__ float Wis[IN_F * HH];
    __shared__ float nfs[32 * IN_F];
    int b = blockIdx.x;
    int t = threadIdx.x;

    for (int i = t; i < IN_F * HH / 4; i += 256)
        reinterpret_cast<float4*>(Wis)[i] = reinterpret_cast<const float4*>(Wi)[i];
    {
        const float4* nf4 = reinterpret_cast<const float4*>(nf + (long)b * 32 * IN_F);
        for (int i = t; i < 32 * IN_F / 4; i += 256)
            reinterpret_cast<float4*>(nfs)[i] = nf4[i];
    }
    __syncthreads();

    int nl = t >> 3;
    int c0 = (t & 7) * 4;
    float acc[4][4];
#pragma unroll
    for (int hf = 0; hf < 4; ++hf)
#pragma unroll
        for (int j = 0; j < 4; ++j) acc[hf][j] = 0.f;

    const float* nrow = nfs + nl * IN_F;
#pragma unroll 2
    for (int k = 0; k < IN_F; ++k) {
        float a = nrow[k];
#pragma unroll
        for (int hf = 0; hf < 4; ++hf) {
            float4 wv = *reinterpret_cast<const float4*>(Wis + k * HH + hf * 32 + c0);
            acc[hf][0] += a * wv.x;
            acc[hf][1] += a * wv.y;
            acc[hf][2] += a * wv.z;
            acc[hf][3] += a * wv.w;
        }
    }

    int node = b * 32 + nl;
#pragma unroll
    for (int hf = 0; hf < 4; ++hf) {
        uint_t uh[2], ul[2];
#pragma unroll
        for (int p = 0; p < 2; ++p) {
            float v0 = acc[hf][p * 2], v1 = acc[hf][p * 2 + 1];
            short h0 = f2bf(v0), h1 = f2bf(v1);
            short l0 = f2bf(v0 - bf2f(h0)), l1 = f2bf(v1 - bf2f(h1));
            uh[p] = (uint_t)(ushort_t)h0 | ((uint_t)(ushort_t)h1 << 16);
            ul[p] = (uint_t)(ushort_t)l0 | ((uint_t)(ushort_t)l1 << 16);
        }
        long adr = (long)node * HH + hf * 32 + c0;
        *reinterpret_cast<uint2*>(hhi + adr) = make_uint2(uh[0], uh[1]);
        *reinterpret_cast<uint2*>(hlo + adr) = make_uint2(ul[0], ul[1]);
    }
}

// ============ CSR build ============
__global__ __launch_bounds__(256) void k_hist(const int* __restrict__ dsti, int* __restrict__ deg)
{
    int e = blockIdx.x * 256 + threadIdx.x;
    atomicAdd(&deg[dsti[e]], 1);
}

__global__ __launch_bounds__(256) void k_scan1(const int* __restrict__ deg, int* __restrict__ bsum)
{
    __shared__ int s[256];
    int b = blockIdx.x, t = threadIdx.x;
    int v = 0;
#pragma unroll
    for (int i = 0; i < 4; ++i) v += deg[b * 1024 + t * 4 + i];
    s[t] = v;
    __syncthreads();
    for (int st = 128; st > 0; st >>= 1) {
        if (t < st) s[t] += s[t + st];
        __syncthreads();
    }
    if (t == 0) bsum[b] = s[0];
}

__global__ void k_scan2(int* __restrict__ bsum, int nb)
{
    if (threadIdx.x == 0) {
        int run = 0;
        for (int i = 0; i < nb; ++i) { int v = bsum[i]; bsum[i] = run; run += v; }
    }
}

__global__ __launch_bounds__(256) void k_scan3(
    const int* __restrict__ deg, const int* __restrict__ bsum, int* __restrict__ row_start)
{
    __shared__ int s[256];
    int b = blockIdx.x, t = threadIdx.x;
    int base = b * 1024 + t * 4;
    int d0 = deg[base], d1 = deg[base + 1], d2 = deg[base + 2], d3 = deg[base + 3];
    int local = d0 + d1 + d2 + d3;
    s[t] = local;
    __syncthreads();
    for (int st = 1; st < 256; st <<= 1) {
        int v = (t >= st) ? s[t - st] : 0;
        __syncthreads();
        s[t] += v;
        __syncthreads();
    }
    int excl = s[t] - local + bsum[b];
    row_start[base] = excl;
    row_start[base + 1] = excl + d0;
    row_start[base + 2] = excl + d0 + d1;
    row_start[base + 3] = excl + d0 + d1 + d2;
    if (b == gridDim.x - 1 && t == 255) row_start[NN] = excl + local;
}

__global__ __launch_bounds__(256) void k_fill(
    const int* __restrict__ src, const int* __restrict__ dsti,
    const int* __restrict__ row_start, int* __restrict__ cursor, int* __restrict__ csr_src)
{
    int e = blockIdx.x * 256 + threadIdx.x;
    int d = dsti[e];
    int pos = atomicAdd(&cursor[d], 1);
    csr_src[row_start[d] + pos] = src[e];
}

// ============ weight split f32 -> (hi, lo) bf16 planes ============
__global__ __launch_bounds__(256) void k_split(
    const float* __restrict__ srcw, ushort_t* __restrict__ hi,
    ushort_t* __restrict__ lo, int n)
{
    int i = blockIdx.x * 256 + threadIdx.x;
    if (i >= n) return;
    float a = srcw[i];
    short h = f2bf(a);
    float rem = a - bf2f(h);
    hi[i] = (ushort_t)h;
    lo[i] = (ushort_t)f2bf(rem);
}

// ============ fused gather + x-GEMM ============
__global__ __launch_bounds__(256) void k_x(
    const ushort_t* __restrict__ hhi, const ushort_t* __restrict__ hlo,
    const int* __restrict__ row_start, const int* __restrict__ csr_src,
    const ushort_t* __restrict__ lWhi, const ushort_t* __restrict__ lWlo,
    const float* __restrict__ lb,
    ushort_t* __restrict__ xhi, ushort_t* __restrict__ xlo)
{
    __shared__ float aggs[32 * 128];
    char* abase = (char*)aggs;
    int n0 = blockIdx.x * 32;
    int t = threadIdx.x;
    int w = t >> 6, lane = t & 63;

    for (int i = 0; i < 8; ++i) {
        int nl = w * 8 + i;
        int node = n0 + nl;
        int e0 = row_start[node], e1 = row_start[node + 1];
        float a0 = 0.f, a1 = 0.f;
        int e = e0;
        for (; e + 3 < e1; e += 4) {
            int s0 = csr_src[e], s1 = csr_src[e + 1];
            int s2 = csr_src[e + 2], s3 = csr_src[e + 3];
            uint_t vh0 = *(const uint_t*)(hhi + (long)s0 * HH + lane * 2);
            uint_t vl0 = *(const uint_t*)(hlo + (long)s0 * HH + lane * 2);
            uint_t vh1 = *(const uint_t*)(hhi + (long)s1 * HH + lane * 2);
            uint_t vl1 = *(const uint_t*)(hlo + (long)s1 * HH + lane * 2);
            uint_t vh2 = *(const uint_t*)(hhi + (long)s2 * HH + lane * 2);
            uint_t vl2 = *(const uint_t*)(hlo + (long)s2 * HH + lane * 2);
            uint_t vh3 = *(const uint_t*)(hhi + (long)s3 * HH + lane * 2);
            uint_t vl3 = *(const uint_t*)(hlo + (long)s3 * HH + lane * 2);
            a0 += bitf(vh0 << 16) + bitf(vl0 << 16);
            a1 += bitf(vh0 & 0xffff0000u) + bitf(vl0 & 0xffff0000u);
            a0 += bitf(vh1 << 16) + bitf(vl1 << 16);
            a1 += bitf(vh1 & 0xffff0000u) + bitf(vl1 & 0xffff0000u);
            a0 += bitf(vh2 << 16) + bitf(vl2 << 16);
            a1 += bitf(vh2 & 0xffff0000u) + bitf(vl2 & 0xffff0000u);
            a0 += bitf(vh3 << 16) + bitf(vl3 << 16);
            a1 += bitf(vh3 & 0xffff0000u) + bitf(vl3 & 0xffff0000u);
        }
        for (; e < e1; ++e) {
            int s0 = csr_src[e];
            uint_t vh0 = *(const uint_t*)(hhi + (long)s0 * HH + lane * 2);
            uint_t vl0 = *(const uint_t*)(hlo + (long)s0 * HH + lane * 2);
            a0 += bitf(vh0 << 16) + bitf(vl0 << 16);
            a1 += bitf(vh0 & 0xffff0000u) + bitf(vl0 & 0xffff0000u);
        }
        int swz = (nl & 7) << 4;
        float2 st = make_float2(a0, a1);
        *reinterpret_cast<float2*>(abase + ((nl * 512 + lane * 8) ^ swz)) = st;
    }
    __syncthreads();

    int ng = w >> 1, jg = w & 1;
    int l16 = lane & 15, lq = lane >> 4;

    f32x4 acc[4];
#pragma unroll
    for (int js = 0; js < 4; ++js) acc[js] = (f32x4){0.f, 0.f, 0.f, 0.f};

#pragma unroll
    for (int kk = 0; kk < 4; ++kk) {
        int k0 = kk * 32;
        int nodeL = ng * 16 + l16;
        int kb = (k0 + lq * 8) * 4;
        int swz = (nodeL & 7) << 4;
        float4 f0 = *reinterpret_cast<const float4*>(abase + ((nodeL * 512 + kb) ^ swz));
        float4 f1 = *reinterpret_cast<const float4*>(abase + ((nodeL * 512 + kb + 16) ^ swz));
        float av[8] = {f0.x, f0.y, f0.z, f0.w, f1.x, f1.y, f1.z, f1.w};
        bf16x8 ahi, alo;
#pragma unroll
        for (int e = 0; e < 8; ++e) {
            short hh_ = f2bf(av[e]);
            ahi[e] = hh_;
            alo[e] = f2bf(av[e] - bf2f(hh_));
        }
#pragma unroll
        for (int js = 0; js < 4; ++js) {
            int jrow = jg * 64 + js * 16 + l16;
            bf16x8 Bh = *reinterpret_cast<const bf16x8*>(lWhi + (long)jrow * HH + k0 + lq * 8);
            bf16x8 Bl = *reinterpret_cast<const bf16x8*>(lWlo + (long)jrow * HH + k0 + lq * 8);
            acc[js] = __builtin_amdgcn_mfma_f32_16x16x32_bf16(ahi, Bh, acc[js], 0, 0, 0);
            acc[js] = __builtin_amdgcn_mfma_f32_16x16x32_bf16(ahi, Bl, acc[js], 0, 0, 0);
            acc[js] = __builtin_amdgcn_mfma_f32_16x16x32_bf16(alo, Bh, acc[js], 0, 0, 0);
        }
    }

#pragma unroll
    for (int js = 0; js < 4; ++js) {
        int j = jg * 64 + js * 16 + l16;
        float bj = lb[j];
#pragma unroll
        for (int r = 0; r < 4; ++r) {
            int node = n0 + ng * 16 + lq * 4 + r;
            float v = fmaxf(acc[js][r] + bj, 0.f);
            long adr = (long)node * HH + j;
            short hi_ = f2bf(v);
            xhi[adr] = (ushort_t)hi_;
            xlo[adr] = (ushort_t)f2bf(v - bf2f(hi_));
        }
    }
}

// ============ fused GRU v5: LDS-fed 4-pass ============
// Block: 64 nodes, 512 threads (8 waves: ng = w>>2, og = w&3).
// LDS 128KB: A planes [4][64 rows][256B] swizzled @0; B [2][128 rows][256B] swizzled @64KB.
// B restaged per pass-half (6 stages); inner loop = 2 ds_read_b128 + 3 MFMA per kc.

#define LDSA(p) ((p) * 16384)
#define LDSB(p) (65536 + (p) * 32768)

// stage contiguous global slab into row-swizzled LDS region
__device__ __forceinline__ void stage_slab(
    const ushort_t* __restrict__ g, char* lds, int tid, int nchunk512)
{
    const uint4* g4 = reinterpret_cast<const uint4*>(g);
#pragma unroll
    for (int i = 0; i < 4; ++i) {
        if (i >= nchunk512) break;
        int c = i * 512 + tid;
        int L = c * 16;
        int row = L >> 8, kb = L & 255;
        *reinterpret_cast<uint4*>(lds + row * 256 + (kb ^ ((row & 15) << 4))) = g4[c];
    }
}

__device__ __forceinline__ void gru_half(
    f32x16& acc, const char* smem, int pAhi, int myoff, int rs_my,
    int jjoff, int rs_jj, int lh)
{
    bf16x8 Ahi[8], Alo[8];
#pragma unroll
    for (int kc = 0; kc < 8; ++kc) {
        int kb = kc * 32 + lh * 16;
        Ahi[kc] = *reinterpret_cast<const bf16x8*>(smem + LDSA(pAhi)     + myoff + (kb ^ rs_my));
        Alo[kc] = *reinterpret_cast<const bf16x8*>(smem + LDSA(pAhi + 1) + myoff + (kb ^ rs_my));
    }
#pragma unroll
    for (int kc = 0; kc < 8; ++kc) {
        int kb = kc * 32 + lh * 16;
        bf16x8 wh = *reinterpret_cast<const bf16x8*>(smem + LDSB(0) + jjoff + (kb ^ rs_jj));
        bf16x8 wl = *reinterpret_cast<const bf16x8*>(smem + LDSB(1) + jjoff + (kb ^ rs_jj));
        acc = __builtin_amdgcn_mfma_f32_32x32x16_bf16(Ahi[kc], wh, acc, 0, 0, 0);
        acc = __builtin_amdgcn_mfma_f32_32x32x16_bf16(Ahi[kc], wl, acc, 0, 0, 0);
        acc = __builtin_amdgcn_mfma_f32_32x32x16_bf16(Alo[kc], wh, acc, 0, 0, 0);
    }
}

__global__ void k_gru(
    const ushort_t* __restrict__ xhi, const ushort_t* __restrict__ xlo,
    ushort_t* __restrict__ hhi, ushort_t* __restrict__ hlo,
    const ushort_t* __restrict__ Wihhi, const ushort_t* __restrict__ Wihlo,
    const ushort_t* __restrict__ Whhhi, const ushort_t* __restrict__ Whhlo,
    const float* __restrict__ bi, const float* __restrict__ bh)
{
    __shared__ uint4 smem4[131072 / 16];
    char* smem = (char*)smem4;

    int t = threadIdx.x;
    int w = t >> 6, lane = t & 63;
    int ng = w >> 2, og = w & 3;
    int l31 = lane & 31, lh = lane >> 5;
    int n0 = blockIdx.x * 64;
    int myrow = ng * 32 + l31;
    int jj = og * 32 + l31;
    int myoff = myrow * 256, rs_my = (myrow & 15) << 4;
    int jjoff = jj * 256,   rs_jj = (jj & 15) << 4;

    // ---- stage A planes (once) + first B (Whh_n) ----
    stage_slab(xhi + (long)n0 * HH, smem + LDSA(0), t, 2);
    stage_slab(xlo + (long)n0 * HH, smem + LDSA(1), t, 2);
    stage_slab(hhi + (long)n0 * HH, smem + LDSA(2), t, 2);
    stage_slab(hlo + (long)n0 * HH, smem + LDSA(3), t, 2);
    stage_slab(Whhhi + 256 * HH, smem + LDSB(0), t, 4);
    stage_slab(Whhlo + 256 * HH, smem + LDSB(1), t, 4);
    __syncthreads();

    // ---- pass 1: acc1 = h @ Whh_n ----
    f32x16 acc1;
#pragma unroll
    for (int i = 0; i < 16; ++i) acc1[i] = 0.f;
    gru_half(acc1, smem, 2, myoff, rs_my, jjoff, rs_jj, lh);

    // ---- pass 2: acc2 = x @ Wih_r + h @ Whh_r; fold rn ----
    f32x16 acc2;
#pragma unroll
    for (int i = 0; i < 16; ++i) acc2[i] = 0.f;
    __syncthreads();
    stage_slab(Wihhi, smem + LDSB(0), t, 4);
    stage_slab(Wihlo, smem + LDSB(1), t, 4);
    __syncthreads();
    gru_half(acc2, smem, 0, myoff, rs_my, jjoff, rs_jj, lh);
    __syncthreads();
    stage_slab(Whhhi, smem + LDSB(0), t, 4);
    stage_slab(Whhlo, smem + LDSB(1), t, 4);
    __syncthreads();
    gru_half(acc2, smem, 2, myoff, rs_my, jjoff, rs_jj, lh);
    {
        float bR = bi[jj] + bh[jj];
        float bNh = bh[256 + jj];
#pragma unroll
        for (int i = 0; i < 16; ++i)
            acc1[i] = sigmoidf_(acc2[i] + bR) * (acc1[i] + bNh);
    }

    // ---- pass 3: acc2 = x @ Wih_n; fold n = tanh ----
#pragma unroll
    for (int i = 0; i < 16; ++i) acc2[i] = 0.f;
    __syncthreads();
    stage_slab(Wihhi + 256 * HH, smem + LDSB(0), t, 4);
    stage_slab(Wihlo + 256 * HH, smem + LDSB(1), t, 4);
    __syncthreads();
    gru_half(acc2, smem, 0, myoff, rs_my, jjoff, rs_jj, lh);
    {
        float bNi = bi[256 + jj];
#pragma unroll
        for (int i = 0; i < 16; ++i)
            acc1[i] = tanhf_(acc2[i] + bNi + acc1[i]);
    }

    // ---- pass 4: acc2 = x @ Wih_z + h @ Whh_z ----
#pragma unroll
    for (int i = 0; i < 16; ++i) acc2[i] = 0.f;
    __syncthreads();
    stage_slab(Wihhi + 128 * HH, smem + LDSB(0), t, 4);
    stage_slab(Wihlo + 128 * HH, smem + LDSB(1), t, 4);
    __syncthreads();
    gru_half(acc2, smem, 0, myoff, rs_my, jjoff, rs_jj, lh);
    __syncthreads();
    stage_slab(Whhhi + 128 * HH, smem + LDSB(0), t, 4);
    stage_slab(Whhlo + 128 * HH, smem + LDSB(1), t, 4);
    __syncthreads();
    gru_half(acc2, smem, 2, myoff, rs_my, jjoff, rs_jj, lh);

    // ---- epilogue: z = sigmoid(acc2 + bZ); h' = (1-z)*n + z*h_old ----
    {
        float bZ = bi[128 + jj] + bh[128 + jj];
        int kb2 = 2 * jj;
#pragma unroll
        for (int reg = 0; reg < 16; ++reg) {
            int ndl = ng * 32 + (reg & 3) + 8 * (reg >> 2) + 4 * lh;
            long adr = (long)(n0 + ndl) * HH + jj;
            int rsn = (ndl & 15) << 4;
            float hold = bf2f(*reinterpret_cast<const short*>(smem + LDSA(2) + ndl * 256 + (kb2 ^ rsn)))
                       + bf2f(*reinterpret_cast<const short*>(smem + LDSA(3) + ndl * 256 + (kb2 ^ rsn)));
            float zv = sigmoidf_(acc2[reg] + bZ);
            float hp = (1.f - zv) * acc1[reg] + zv * hold;
            short hi_ = f2bf(hp);
            hhi[adr] = (ushort_t)hi_;
            hlo[adr] = (ushort_t)f2bf(hp - bf2f(hi_));
        }
    }
}

// ============ final: d_out = hhi + hlo (f32) ============
__global__ __launch_bounds__(256) void k_copy(
    const uint_t* __restrict__ hhi, const uint_t* __restrict__ hlo,
    float2* __restrict__ out)
{
    long i = (long)blockIdx.x * 256 + threadIdx.x;
    uint_t vh = hhi[i], vl = hlo[i];
    float2 o;
    o.x = bitf(vh << 16) + bitf(vl << 16);
    o.y = bitf(vh & 0xffff0000u) + bitf(vl & 0xffff0000u);
    out[i] = o;
}

extern "C" void kernel_launch(void* const* d_in, const int* in_sizes, int n_in,
                              void* d_out, int out_size, void* d_ws, size_t ws_size,
                              hipStream_t stream)
{
    const float* nf     = (const float*)d_in[0];
    const int*   src    = (const int*)d_in[1];
    const int*   dsti   = (const int*)d_in[2];
    const float* W_init = (const float*)d_in[3];
    const float* lin_W  = (const float*)d_in[4];
    const float* lin_b  = (const float*)d_in[5];
    const float* Wih    = (const float*)d_in[6];
    const float* Whh    = (const float*)d_in[7];
    const float* bih    = (const float*)d_in[8];
    const float* bhh    = (const float*)d_in[9];

    char* ws = (char*)d_ws;
    ushort_t* hhi = (ushort_t*)ws;
    ushort_t* hlo = (ushort_t*)(ws + (32ull << 20));
    ushort_t* xhi = (ushort_t*)(ws + (64ull << 20));
    ushort_t* xlo = (ushort_t*)(ws + (96ull << 20));
    int* deg    = (int*)(ws + (64ull << 20));
    int* cursor = (int*)(ws + (64ull << 20) + (1 << 20));
    int* bsum   = (int*)(ws + (64ull << 20) + (2 << 20));

    char* ob = (char*)d_out;
    int* row_start = (int*)ob;
    int* csr_src   = (int*)(ob + (1ull << 20));
    ushort_t* lWhi  = (ushort_t*)(ob + (6ull << 20));
    ushort_t* lWlo  = lWhi  + 3 * 128 * 128;
    ushort_t* Wihhi = lWlo  + 3 * 128 * 128;
    ushort_t* Wihlo = Wihhi + 3 * 384 * 128;
    ushort_t* Whhhi = Wihlo + 3 * 384 * 128;
    ushort_t* Whhlo = Whhhi + 3 * 384 * 128;

    k_init_gemm<<<NN / 32, 256, 0, stream>>>(nf, W_init, hhi, hlo);

    hipMemsetAsync(deg, 0, (size_t)NN * 4, stream);
    hipMemsetAsync(cursor, 0, (size_t)NN * 4, stream);
    k_hist<<<EE / 256, 256, 0, stream>>>(dsti, deg);
    k_scan1<<<NN / 1024, 256, 0, stream>>>(deg, bsum);
    k_scan2<<<1, 64, 0, stream>>>(bsum, NN / 1024);
    k_scan3<<<NN / 1024, 256, 0, stream>>>(deg, bsum, row_start);
    k_fill<<<EE / 256, 256, 0, stream>>>(src, dsti, row_start, cursor, csr_src);

    k_split<<<(3 * 128 * 128 + 255) / 256, 256, 0, stream>>>(lin_W, lWhi, lWlo, 3 * 128 * 128);
    k_split<<<(3 * 384 * 128 + 255) / 256, 256, 0, stream>>>(Wih, Wihhi, Wihlo, 3 * 384 * 128);
    k_split<<<(3 * 384 * 128 + 255) / 256, 256, 0, stream>>>(Whh, Whhhi, Whhlo, 3 * 384 * 128);

    for (int l = 0; l < LL; ++l) {
        k_x<<<NN / 32, 256, 0, stream>>>(
            hhi, hlo, row_start, csr_src,
            lWhi + (long)l * 128 * 128, lWlo + (long)l * 128 * 128,
            lin_b + (long)l * 128, xhi, xlo);
        k_gru<<<NN / 64, 512, 0, stream>>>(
            xhi, xlo, hhi, hlo,
            Wihhi + (long)l * 384 * 128, Wihlo + (long)l * 384 * 128,
            Whhhi + (long)l * 384 * 128, Whhlo + (long)l * 384 * 128,
            bih + (long)l * 384, bhh + (long)l * 384);
    }

    k_copy<<<NN * HH / 2 / 256, 256, 0, stream>>>((const uint_t*)hhi, (const uint_t*)hlo, (float2*)d_out);
}

// Round 10
// 972.923 us; speedup vs baseline: 3.7980x; 1.0086x over previous
//
#include <hip/hip_runtime.h>
#include <hip/hip_bf16.h>

#define NN 131072
#define EE 1048576
#define IN_F 74
#define HH 128
#define LL 3

using f32x4  = __attribute__((ext_vector_type(4))) float;
using f32x16 = __attribute__((ext_vector_type(16))) float;
using bf16x8 = __attribute__((ext_vector_type(8))) short;
typedef unsigned short ushort_t;
typedef unsigned int uint_t;

__device__ __forceinline__ short f2bf(float f) {
    __hip_bfloat16 b = __float2bfloat16(f);
    return __builtin_bit_cast(short, b);
}
__device__ __forceinline__ float bf2f(short s) {
    unsigned int u = ((unsigned int)(unsigned short)s) << 16;
    return __builtin_bit_cast(float, u);
}
__device__ __forceinline__ float bitf(uint_t u) { return __builtin_bit_cast(float, u); }
__device__ __forceinline__ float sigmoidf_(float x) { return 1.f / (1.f + __expf(-x)); }
__device__ __forceinline__ float tanhf_(float x)
{
    x = fminf(fmaxf(x, -15.f), 15.f);
    float e2 = __expf(2.f * x);
    return (e2 - 1.f) / (e2 + 1.f);
}

// ============ init: h = nf @ W_init -> bf16 hi/lo planes ============
__global__ __launch_bounds__(256) void k_init_gemm(
    const float* __restrict__ nf, const float* __restrict__ Wi,
    ushort_t* __restrict__ hhi, ushort_t* __restrict__ hlo)
{
    __shared__ float Wis[IN_F * HH];
    __shared__ float nfs[32 * IN_F];
    int b = blockIdx.x;
    int t = threadIdx.x;

    for (int i = t; i < IN_F * HH / 4; i += 256)
        reinterpret_cast<float4*>(Wis)[i] = reinterpret_cast<const float4*>(Wi)[i];
    {
        const float4* nf4 = reinterpret_cast<const float4*>(nf + (long)b * 32 * IN_F);
        for (int i = t; i < 32 * IN_F / 4; i += 256)
            reinterpret_cast<float4*>(nfs)[i] = nf4[i];
    }
    __syncthreads();

    int nl = t >> 3;
    int c0 = (t & 7) * 4;
    float acc[4][4];
#pragma unroll
    for (int hf = 0; hf < 4; ++hf)
#pragma unroll
        for (int j = 0; j < 4; ++j) acc[hf][j] = 0.f;

    const float* nrow = nfs + nl * IN_F;
#pragma unroll 2
    for (int k = 0; k < IN_F; ++k) {
        float a = nrow[k];
#pragma unroll
        for (int hf = 0; hf < 4; ++hf) {
            float4 wv = *reinterpret_cast<const float4*>(Wis + k * HH + hf * 32 + c0);
            acc[hf][0] += a * wv.x;
            acc[hf][1] += a * wv.y;
            acc[hf][2] += a * wv.z;
            acc[hf][3] += a * wv.w;
        }
    }

    int node = b * 32 + nl;
#pragma unroll
    for (int hf = 0; hf < 4; ++hf) {
        uint_t uh[2], ul[2];
#pragma unroll
        for (int p = 0; p < 2; ++p) {
            float v0 = acc[hf][p * 2], v1 = acc[hf][p * 2 + 1];
            short h0 = f2bf(v0), h1 = f2bf(v1);
            short l0 = f2bf(v0 - bf2f(h0)), l1 = f2bf(v1 - bf2f(h1));
            uh[p] = (uint_t)(ushort_t)h0 | ((uint_t)(ushort_t)h1 << 16);
            ul[p] = (uint_t)(ushort_t)l0 | ((uint_t)(ushort_t)l1 << 16);
        }
        long adr = (long)node * HH + hf * 32 + c0;
        *reinterpret_cast<uint2*>(hhi + adr) = make_uint2(uh[0], uh[1]);
        *reinterpret_cast<uint2*>(hlo + adr) = make_uint2(ul[0], ul[1]);
    }
}

// ============ CSR build ============
__global__ __launch_bounds__(256) void k_hist(const int* __restrict__ dsti, int* __restrict__ deg)
{
    int e = blockIdx.x * 256 + threadIdx.x;
    atomicAdd(&deg[dsti[e]], 1);
}

__global__ __launch_bounds__(256) void k_scan1(const int* __restrict__ deg, int* __restrict__ bsum)
{
    __shared__ int s[256];
    int b = blockIdx.x, t = threadIdx.x;
    int v = 0;
#pragma unroll
    for (int i = 0; i < 4; ++i) v += deg[b * 1024 + t * 4 + i];
    s[t] = v;
    __syncthreads();
    for (int st = 128; st > 0; st >>= 1) {
        if (t < st) s[t] += s[t + st];
        __syncthreads();
    }
    if (t == 0) bsum[b] = s[0];
}

__global__ void k_scan2(int* __restrict__ bsum, int nb)
{
    if (threadIdx.x == 0) {
        int run = 0;
        for (int i = 0; i < nb; ++i) { int v = bsum[i]; bsum[i] = run; run += v; }
    }
}

__global__ __launch_bounds__(256) void k_scan3(
    const int* __restrict__ deg, const int* __restrict__ bsum, int* __restrict__ row_start)
{
    __shared__ int s[256];
    int b = blockIdx.x, t = threadIdx.x;
    int base = b * 1024 + t * 4;
    int d0 = deg[base], d1 = deg[base + 1], d2 = deg[base + 2], d3 = deg[base + 3];
    int local = d0 + d1 + d2 + d3;
    s[t] = local;
    __syncthreads();
    for (int st = 1; st < 256; st <<= 1) {
        int v = (t >= st) ? s[t - st] : 0;
        __syncthreads();
        s[t] += v;
        __syncthreads();
    }
    int excl = s[t] - local + bsum[b];
    row_start[base] = excl;
    row_start[base + 1] = excl + d0;
    row_start[base + 2] = excl + d0 + d1;
    row_start[base + 3] = excl + d0 + d1 + d2;
    if (b == gridDim.x - 1 && t == 255) row_start[NN] = excl + local;
}

__global__ __launch_bounds__(256) void k_fill(
    const int* __restrict__ src, const int* __restrict__ dsti,
    const int* __restrict__ row_start, int* __restrict__ cursor, int* __restrict__ csr_src)
{
    int e = blockIdx.x * 256 + threadIdx.x;
    int d = dsti[e];
    int pos = atomicAdd(&cursor[d], 1);
    csr_src[row_start[d] + pos] = src[e];
}

// ============ weight split f32 -> (hi, lo) bf16 planes ============
__global__ __launch_bounds__(256) void k_split(
    const float* __restrict__ srcw, ushort_t* __restrict__ hi,
    ushort_t* __restrict__ lo, int n)
{
    int i = blockIdx.x * 256 + threadIdx.x;
    if (i >= n) return;
    float a = srcw[i];
    short h = f2bf(a);
    float rem = a - bf2f(h);
    hi[i] = (ushort_t)h;
    lo[i] = (ushort_t)f2bf(rem);
}

// ============ fused gather + x-GEMM v2 ============
// Block: 32 nodes, 4 waves. Indices staged in LDS; lanes 0-31 gather hi plane
// (4 cols via uint2), lanes 32-63 the lo plane; shfl_xor(32) combine; unroll-8.
#define EIDX_CAP 1024

template <bool LDSIDX>
__device__ __forceinline__ void gather_node(
    const ushort_t* __restrict__ plane, const int* __restrict__ eidx,
    const int* __restrict__ csr_src, int estart, int e0, int e1, int c4,
    float& a0, float& a1, float& a2, float& a3)
{
    int e = e0;
    for (; e + 7 < e1; e += 8) {
        uint2 v[8];
#pragma unroll
        for (int u = 0; u < 8; ++u) {
            int s = LDSIDX ? eidx[e + u] : csr_src[estart + e + u];
            v[u] = *reinterpret_cast<const uint2*>(plane + (long)s * HH + c4);
        }
#pragma unroll
        for (int u = 0; u < 8; ++u) {
            a0 += bitf(v[u].x << 16);
            a1 += bitf(v[u].x & 0xffff0000u);
            a2 += bitf(v[u].y << 16);
            a3 += bitf(v[u].y & 0xffff0000u);
        }
    }
    for (; e < e1; ++e) {
        int s = LDSIDX ? eidx[e] : csr_src[estart + e];
        uint2 vv = *reinterpret_cast<const uint2*>(plane + (long)s * HH + c4);
        a0 += bitf(vv.x << 16);
        a1 += bitf(vv.x & 0xffff0000u);
        a2 += bitf(vv.y << 16);
        a3 += bitf(vv.y & 0xffff0000u);
    }
}

__global__ __launch_bounds__(256) void k_x(
    const ushort_t* __restrict__ hhi, const ushort_t* __restrict__ hlo,
    const int* __restrict__ row_start, const int* __restrict__ csr_src,
    const ushort_t* __restrict__ lWhi, const ushort_t* __restrict__ lWlo,
    const float* __restrict__ lb,
    ushort_t* __restrict__ xhi, ushort_t* __restrict__ xlo)
{
    __shared__ float aggs[32 * 128];   // 16 KB
    __shared__ int eidx[EIDX_CAP];     // 4 KB
    char* abase = (char*)aggs;
    int n0 = blockIdx.x * 32;
    int t = threadIdx.x;
    int w = t >> 6, lane = t & 63;

    int estart = row_start[n0];
    int ecount = row_start[n0 + 32] - estart;
    bool inl = (ecount <= EIDX_CAP);
    for (int i = t; i < ecount && i < EIDX_CAP; i += 256)
        eidx[i] = csr_src[estart + i];
    __syncthreads();

    const ushort_t* plane = (lane >= 32) ? hlo : hhi;
    int c4 = (lane & 31) * 4;

    for (int i = 0; i < 8; ++i) {
        int nl = w * 8 + i;
        int node = n0 + nl;
        int e0 = row_start[node] - estart;
        int e1 = row_start[node + 1] - estart;
        float a0 = 0.f, a1 = 0.f, a2 = 0.f, a3 = 0.f;
        if (inl)
            gather_node<true>(plane, eidx, csr_src, estart, e0, e1, c4, a0, a1, a2, a3);
        else
            gather_node<false>(plane, eidx, csr_src, estart, e0, e1, c4, a0, a1, a2, a3);
        // combine hi (lanes 0-31) + lo (lanes 32-63)
        a0 += __shfl_xor(a0, 32, 64);
        a1 += __shfl_xor(a1, 32, 64);
        a2 += __shfl_xor(a2, 32, 64);
        a3 += __shfl_xor(a3, 32, 64);
        if (lane < 32) {
            int swz = (nl & 7) << 4;
            float4 st = make_float4(a0, a1, a2, a3);
            *reinterpret_cast<float4*>(abase + ((nl * 512 + c4 * 4) ^ swz)) = st;
        }
    }
    __syncthreads();

    // ---- GEMM: x = relu(agg @ lW^T + lb) ----
    int ng = w >> 1, jg = w & 1;
    int l16 = lane & 15, lq = lane >> 4;

    f32x4 acc[4];
#pragma unroll
    for (int js = 0; js < 4; ++js) acc[js] = (f32x4){0.f, 0.f, 0.f, 0.f};

#pragma unroll
    for (int kk = 0; kk < 4; ++kk) {
        int k0 = kk * 32;
        int nodeL = ng * 16 + l16;
        int kb = (k0 + lq * 8) * 4;
        int swz = (nodeL & 7) << 4;
        float4 f0 = *reinterpret_cast<const float4*>(abase + ((nodeL * 512 + kb) ^ swz));
        float4 f1 = *reinterpret_cast<const float4*>(abase + ((nodeL * 512 + kb + 16) ^ swz));
        float av[8] = {f0.x, f0.y, f0.z, f0.w, f1.x, f1.y, f1.z, f1.w};
        bf16x8 ahi, alo;
#pragma unroll
        for (int e = 0; e < 8; ++e) {
            short hh_ = f2bf(av[e]);
            ahi[e] = hh_;
            alo[e] = f2bf(av[e] - bf2f(hh_));
        }
#pragma unroll
        for (int js = 0; js < 4; ++js) {
            int jrow = jg * 64 + js * 16 + l16;
            bf16x8 Bh = *reinterpret_cast<const bf16x8*>(lWhi + (long)jrow * HH + k0 + lq * 8);
            bf16x8 Bl = *reinterpret_cast<const bf16x8*>(lWlo + (long)jrow * HH + k0 + lq * 8);
            acc[js] = __builtin_amdgcn_mfma_f32_16x16x32_bf16(ahi, Bh, acc[js], 0, 0, 0);
            acc[js] = __builtin_amdgcn_mfma_f32_16x16x32_bf16(ahi, Bl, acc[js], 0, 0, 0);
            acc[js] = __builtin_amdgcn_mfma_f32_16x16x32_bf16(alo, Bh, acc[js], 0, 0, 0);
        }
    }

#pragma unroll
    for (int js = 0; js < 4; ++js) {
        int j = jg * 64 + js * 16 + l16;
        float bj = lb[j];
#pragma unroll
        for (int r = 0; r < 4; ++r) {
            int node = n0 + ng * 16 + lq * 4 + r;
            float v = fmaxf(acc[js][r] + bj, 0.f);
            long adr = (long)node * HH + j;
            short hi_ = f2bf(v);
            xhi[adr] = (ushort_t)hi_;
            xlo[adr] = (ushort_t)f2bf(v - bf2f(hi_));
        }
    }
}

// ============ fused GRU v5: LDS-fed 4-pass (round-9, unchanged) ============
#define LDSA(p) ((p) * 16384)
#define LDSB(p) (65536 + (p) * 32768)

__device__ __forceinline__ void stage_slab(
    const ushort_t* __restrict__ g, char* lds, int tid, int nchunk512)
{
    const uint4* g4 = reinterpret_cast<const uint4*>(g);
#pragma unroll
    for (int i = 0; i < 4; ++i) {
        if (i >= nchunk512) break;
        int c = i * 512 + tid;
        int L = c * 16;
        int row = L >> 8, kb = L & 255;
        *reinterpret_cast<uint4*>(lds + row * 256 + (kb ^ ((row & 15) << 4))) = g4[c];
    }
}

__device__ __forceinline__ void gru_half(
    f32x16& acc, const char* smem, int pAhi, int myoff, int rs_my,
    int jjoff, int rs_jj, int lh)
{
    bf16x8 Ahi[8], Alo[8];
#pragma unroll
    for (int kc = 0; kc < 8; ++kc) {
        int kb = kc * 32 + lh * 16;
        Ahi[kc] = *reinterpret_cast<const bf16x8*>(smem + LDSA(pAhi)     + myoff + (kb ^ rs_my));
        Alo[kc] = *reinterpret_cast<const bf16x8*>(smem + LDSA(pAhi + 1) + myoff + (kb ^ rs_my));
    }
#pragma unroll
    for (int kc = 0; kc < 8; ++kc) {
        int kb = kc * 32 + lh * 16;
        bf16x8 wh = *reinterpret_cast<const bf16x8*>(smem + LDSB(0) + jjoff + (kb ^ rs_jj));
        bf16x8 wl = *reinterpret_cast<const bf16x8*>(smem + LDSB(1) + jjoff + (kb ^ rs_jj));
        acc = __builtin_amdgcn_mfma_f32_32x32x16_bf16(Ahi[kc], wh, acc, 0, 0, 0);
        acc = __builtin_amdgcn_mfma_f32_32x32x16_bf16(Ahi[kc], wl, acc, 0, 0, 0);
        acc = __builtin_amdgcn_mfma_f32_32x32x16_bf16(Alo[kc], wh, acc, 0, 0, 0);
    }
}

__global__ void k_gru(
    const ushort_t* __restrict__ xhi, const ushort_t* __restrict__ xlo,
    ushort_t* __restrict__ hhi, ushort_t* __restrict__ hlo,
    const ushort_t* __restrict__ Wihhi, const ushort_t* __restrict__ Wihlo,
    const ushort_t* __restrict__ Whhhi, const ushort_t* __restrict__ Whhlo,
    const float* __restrict__ bi, const float* __restrict__ bh)
{
    __shared__ uint4 smem4[131072 / 16];
    char* smem = (char*)smem4;

    int t = threadIdx.x;
    int w = t >> 6, lane = t & 63;
    int ng = w >> 2, og = w & 3;
    int l31 = lane & 31, lh = lane >> 5;
    int n0 = blockIdx.x * 64;
    int myrow = ng * 32 + l31;
    int jj = og * 32 + l31;
    int myoff = myrow * 256, rs_my = (myrow & 15) << 4;
    int jjoff = jj * 256,   rs_jj = (jj & 15) << 4;

    stage_slab(xhi + (long)n0 * HH, smem + LDSA(0), t, 2);
    stage_slab(xlo + (long)n0 * HH, smem + LDSA(1), t, 2);
    stage_slab(hhi + (long)n0 * HH, smem + LDSA(2), t, 2);
    stage_slab(hlo + (long)n0 * HH, smem + LDSA(3), t, 2);
    stage_slab(Whhhi + 256 * HH, smem + LDSB(0), t, 4);
    stage_slab(Whhlo + 256 * HH, smem + LDSB(1), t, 4);
    __syncthreads();

    f32x16 acc1;
#pragma unroll
    for (int i = 0; i < 16; ++i) acc1[i] = 0.f;
    gru_half(acc1, smem, 2, myoff, rs_my, jjoff, rs_jj, lh);

    f32x16 acc2;
#pragma unroll
    for (int i = 0; i < 16; ++i) acc2[i] = 0.f;
    __syncthreads();
    stage_slab(Wihhi, smem + LDSB(0), t, 4);
    stage_slab(Wihlo, smem + LDSB(1), t, 4);
    __syncthreads();
    gru_half(acc2, smem, 0, myoff, rs_my, jjoff, rs_jj, lh);
    __syncthreads();
    stage_slab(Whhhi, smem + LDSB(0), t, 4);
    stage_slab(Whhlo, smem + LDSB(1), t, 4);
    __syncthreads();
    gru_half(acc2, smem, 2, myoff, rs_my, jjoff, rs_jj, lh);
    {
        float bR = bi[jj] + bh[jj];
        float bNh = bh[256 + jj];
#pragma unroll
        for (int i = 0; i < 16; ++i)
            acc1[i] = sigmoidf_(acc2[i] + bR) * (acc1[i] + bNh);
    }

#pragma unroll
    for (int i = 0; i < 16; ++i) acc2[i] = 0.f;
    __syncthreads();
    stage_slab(Wihhi + 256 * HH, smem + LDSB(0), t, 4);
    stage_slab(Wihlo + 256 * HH, smem + LDSB(1), t, 4);
    __syncthreads();
    gru_half(acc2, smem, 0, myoff, rs_my, jjoff, rs_jj, lh);
    {
        float bNi = bi[256 + jj];
#pragma unroll
        for (int i = 0; i < 16; ++i)
            acc1[i] = tanhf_(acc2[i] + bNi + acc1[i]);
    }

#pragma unroll
    for (int i = 0; i < 16; ++i) acc2[i] = 0.f;
    __syncthreads();
    stage_slab(Wihhi + 128 * HH, smem + LDSB(0), t, 4);
    stage_slab(Wihlo + 128 * HH, smem + LDSB(1), t, 4);
    __syncthreads();
    gru_half(acc2, smem, 0, myoff, rs_my, jjoff, rs_jj, lh);
    __syncthreads();
    stage_slab(Whhhi + 128 * HH, smem + LDSB(0), t, 4);
    stage_slab(Whhlo + 128 * HH, smem + LDSB(1), t, 4);
    __syncthreads();
    gru_half(acc2, smem, 2, myoff, rs_my, jjoff, rs_jj, lh);

    {
        float bZ = bi[128 + jj] + bh[128 + jj];
        int kb2 = 2 * jj;
#pragma unroll
        for (int reg = 0; reg < 16; ++reg) {
            int ndl = ng * 32 + (reg & 3) + 8 * (reg >> 2) + 4 * lh;
            long adr = (long)(n0 + ndl) * HH + jj;
            int rsn = (ndl & 15) << 4;
            float hold = bf2f(*reinterpret_cast<const short*>(smem + LDSA(2) + ndl * 256 + (kb2 ^ rsn)))
                       + bf2f(*reinterpret_cast<const short*>(smem + LDSA(3) + ndl * 256 + (kb2 ^ rsn)));
            float zv = sigmoidf_(acc2[reg] + bZ);
            float hp = (1.f - zv) * acc1[reg] + zv * hold;
            short hi_ = f2bf(hp);
            hhi[adr] = (ushort_t)hi_;
            hlo[adr] = (ushort_t)f2bf(hp - bf2f(hi_));
        }
    }
}

// ============ final: d_out = hhi + hlo (f32) ============
__global__ __launch_bounds__(256) void k_copy(
    const uint_t* __restrict__ hhi, const uint_t* __restrict__ hlo,
    float2* __restrict__ out)
{
    long i = (long)blockIdx.x * 256 + threadIdx.x;
    uint_t vh = hhi[i], vl = hlo[i];
    float2 o;
    o.x = bitf(vh << 16) + bitf(vl << 16);
    o.y = bitf(vh & 0xffff0000u) + bitf(vl & 0xffff0000u);
    out[i] = o;
}

extern "C" void kernel_launch(void* const* d_in, const int* in_sizes, int n_in,
                              void* d_out, int out_size, void* d_ws, size_t ws_size,
                              hipStream_t stream)
{
    const float* nf     = (const float*)d_in[0];
    const int*   src    = (const int*)d_in[1];
    const int*   dsti   = (const int*)d_in[2];
    const float* W_init = (const float*)d_in[3];
    const float* lin_W  = (const float*)d_in[4];
    const float* lin_b  = (const float*)d_in[5];
    const float* Wih    = (const float*)d_in[6];
    const float* Whh    = (const float*)d_in[7];
    const float* bih    = (const float*)d_in[8];
    const float* bhh    = (const float*)d_in[9];

    char* ws = (char*)d_ws;
    ushort_t* hhi = (ushort_t*)ws;
    ushort_t* hlo = (ushort_t*)(ws + (32ull << 20));
    ushort_t* xhi = (ushort_t*)(ws + (64ull << 20));
    ushort_t* xlo = (ushort_t*)(ws + (96ull << 20));
    int* deg    = (int*)(ws + (64ull << 20));
    int* cursor = (int*)(ws + (64ull << 20) + (1 << 20));
    int* bsum   = (int*)(ws + (64ull << 20) + (2 << 20));

    char* ob = (char*)d_out;
    int* row_start = (int*)ob;
    int* csr_src   = (int*)(ob + (1ull << 20));
    ushort_t* lWhi  = (ushort_t*)(ob + (6ull << 20));
    ushort_t* lWlo  = lWhi  + 3 * 128 * 128;
    ushort_t* Wihhi = lWlo  + 3 * 128 * 128;
    ushort_t* Wihlo = Wihhi + 3 * 384 * 128;
    ushort_t* Whhhi = Wihlo + 3 * 384 * 128;
    ushort_t* Whhlo = Whhhi + 3 * 384 * 128;

    k_init_gemm<<<NN / 32, 256, 0, stream>>>(nf, W_init, hhi, hlo);

    hipMemsetAsync(deg, 0, (size_t)NN * 4, stream);
    hipMemsetAsync(cursor, 0, (size_t)NN * 4, stream);
    k_hist<<<EE / 256, 256, 0, stream>>>(dsti, deg);
    k_scan1<<<NN / 1024, 256, 0, stream>>>(deg, bsum);
    k_scan2<<<1, 64, 0, stream>>>(bsum, NN / 1024);
    k_scan3<<<NN / 1024, 256, 0, stream>>>(deg, bsum, row_start);
    k_fill<<<EE / 256, 256, 0, stream>>>(src, dsti, row_start, cursor, csr_src);

    k_split<<<(3 * 128 * 128 + 255) / 256, 256, 0, stream>>>(lin_W, lWhi, lWlo, 3 * 128 * 128);
    k_split<<<(3 * 384 * 128 + 255) / 256, 256, 0, stream>>>(Wih, Wihhi, Wihlo, 3 * 384 * 128);
    k_split<<<(3 * 384 * 128 + 255) / 256, 256, 0, stream>>>(Whh, Whhhi, Whhlo, 3 * 384 * 128);

    for (int l = 0; l < LL; ++l) {
        k_x<<<NN / 32, 256, 0, stream>>>(
            hhi, hlo, row_start, csr_src,
            lWhi + (long)l * 128 * 128, lWlo + (long)l * 128 * 128,
            lin_b + (long)l * 128, xhi, xlo);
        k_gru<<<NN / 64, 512, 0, stream>>>(
            xhi, xlo, hhi, hlo,
            Wihhi + (long)l * 384 * 128, Wihlo + (long)l * 384 * 128,
            Whhhi + (long)l * 384 * 128, Whhlo + (long)l * 384 * 128,
            bih + (long)l * 384, bhh + (long)l * 384);
    }

    k_copy<<<NN * HH / 2 / 256, 256, 0, stream>>>((const uint_t*)hhi, (const uint_t*)hlo, (float2*)d_out);
}